// Round 6
// baseline (3167.205 us; speedup 1.0000x reference)
//
#include <hip/hip_runtime.h>

#define TT 4000   // timesteps
#define HH 64     // hidden
#define NB 256    // batch
#define EE 128    // fc out

typedef __attribute__((ext_vector_type(2))) _Float16 h2;
typedef __attribute__((ext_vector_type(8))) _Float16 h8;

__device__ __forceinline__ float ftanh(float x) {
    return fmaf(2.f, __builtin_amdgcn_rcpf(1.f + __expf(-2.f * x)), -1.f);
}

#if __has_builtin(__builtin_amdgcn_fdot2)
#define FDOT2(a, b, c) __builtin_amdgcn_fdot2((a), (b), (c), false)
#else
#define FDOT2(a, b, c) fmaf((float)(a).x, (float)(b).x, fmaf((float)(a).y, (float)(b).y, (c)))
#endif

// h2 sub-extract from h8 register (sub-register addressing, no memory).
#define H2V(V, i) (__builtin_shufflevector((V), (V), 2 * (i), 2 * (i) + 1))

// DPP helpers (VALU pipe, no LDS). ctrl must be an ICE -> template param.
template <int CTRL>
__device__ __forceinline__ float dpp_mov(float v) {
    return __int_as_float(__builtin_amdgcn_update_dpp(
        0, __float_as_int(v), CTRL, 0xF, 0xF, true));
}
#define DPP_XOR1 0xB1   // quad_perm [1,0,3,2]  (flip s)      [HW-verified R8/R9]
#define DPP_XOR2 0x4E   // quad_perm [2,3,0,1]  (flip u)      [HW-verified R8/R9]
#define DPP_FB   0x44   // quad_perm [0,1,0,1]  (broadcast u=0 per s)
#define DPP_OB   0xEE   // quad_perm [2,3,2,3]  (broadcast u=1 per s)
#define DPP_SHR4 0x114  // row_shr:4            (p=0 quad -> p=1 quad) [R13-verified]

#define CVT2(d0, d1, s) h2 d0 = h2{(_Float16)(s).x, (_Float16)(s).y}, \
                           d1 = h2{(_Float16)(s).z, (_Float16)(s).w};

// R19: two independent recurrences per instruction stream. Config evidence:
// 1 wave/SIMD (256thr) is strictly best (R13/R18: 2 waves/SIMD lose —
// barrier-lockstep waves double issue+DS without hiding stalls); marginal
// instrs cost full issue (R15/R18); explicit scheduling is null (R17). The
// step (1131 cyc) = per-wave issue (~450) + ~600-700 cyc of SERIAL latency
// (LDS write-drain->barrier->read ~250-300, dot-chain tails + exp/tanh
// trans latency ~300-400) that nothing currently overlaps. Fix: each block
// now runs TWO batch elements (grid 128): same gate rows -> weights shared
// (zero extra weight VGPRs); only state/accs/h-reads double. Element Q's
// dot issue fills element P's latencies and vice versa -> the ~600-cyc
// serial tail is paid once for two elements. Predicted 2-elem step
// ~850-950 cyc < 1131.
//
// lane = 16*rowgrp + 8*nn + 4*p + 2*u + s ; na = w*8 + rowgrp*2 + nn (0..31),
// nb = na+32 ; gate = p + 2u (p=0 quad: i,i,g,g ; p=1 quad: f,f,o,o),
// s = k-half AND layer assignment.
//
// Layer pipelining (verified R3-R10): iter t computes L0 gates(t) from
// h0(t-1) and L1 gates(t-1) from {h1(t-2), h0(t-1)}; s=0 lanes run the L0
// act/cell path, s=1 the L1 path. 1 barrier/step, h fp16 double-buffered.
__global__ __launch_bounds__(256, 1)
void lstm2_fc_kernel(const float* __restrict__ x,      // [B, T, 1]
                     const float* __restrict__ W_ih0,  // [256, 1]
                     const float* __restrict__ W_hh0,  // [256, 64]
                     const float* __restrict__ b_ih0,  // [256]
                     const float* __restrict__ b_hh0,  // [256]
                     const float* __restrict__ W_ih1,  // [256, 64]
                     const float* __restrict__ W_hh1,  // [256, 64]
                     const float* __restrict__ b_ih1,  // [256]
                     const float* __restrict__ b_hh1,  // [256]
                     const float* __restrict__ W_fc,   // [128, 64]
                     const float* __restrict__ b_fc,   // [128]
                     float* __restrict__ out)          // [B, 128]
{
    const int b    = blockIdx.x;      // 0..127 -> batch pair (2b, 2b+1)
    const int tid  = threadIdx.x;     // 0..255
    const int w    = tid >> 6;        // wave 0..3
    const int lane = tid & 63;
    const int ss   = lane & 1;        // k-half AND layer assignment
    const int uu   = (lane >> 1) & 1;
    const int pp   = (lane >> 2) & 1;
    const int nn   = (lane >> 3) & 1;
    const int na   = w * 8 + (lane >> 4) * 2 + nn;   // h-index 0..31
    const int nb   = na + 32;                        // h-index 32..63
    const int gidx = pp + 2 * uu;                    // 0:i 1:f 2:g 3:o

    __shared__ float x_s[2][TT];                          // 32 KB
    __shared__ __align__(16) _Float16 hbuf[2][2][2 * HH]; // [elem][parity][h0|h1]

    for (int t = tid; t < TT; t += 256) {
        x_s[0][t] = x[(size_t)(2 * b + 0) * TT + t];
        x_s[1][t] = x[(size_t)(2 * b + 1) * TT + t];
    }
    {   // zero all 512 halves of hbuf
        _Float16* hz = (_Float16*)hbuf;
        hz[tid] = (_Float16)0.f;
        hz[tid + 256] = (_Float16)0.f;
    }

    const int rowa = gidx * HH + na;   // gate row in [0,256)
    const int rowb = gidx * HH + nb;   // = rowa + 32
    // --- Named-scalar weight load: 6 thirty-two-wide slices -> 96 h2 ---
    // (shared by BOTH batch elements — rows are batch-independent)
    const float4* p0 = (const float4*)(W_hh0 + rowa * HH + ss * 32);
    const float4* p1 = (const float4*)(W_ih1 + rowa * HH + ss * 32);
    const float4* p2 = (const float4*)(W_hh1 + rowa * HH + ss * 32);
    const float4* p3 = (const float4*)(W_hh0 + rowb * HH + ss * 32);
    const float4* p4 = (const float4*)(W_ih1 + rowb * HH + ss * 32);
    const float4* p5 = (const float4*)(W_hh1 + rowb * HH + ss * 32);
    float4 qa0 = p0[0], qa1 = p0[1], qa2 = p0[2], qa3 = p0[3];
    float4 qa4 = p0[4], qa5 = p0[5], qa6 = p0[6], qa7 = p0[7];
    float4 qb0 = p1[0], qb1 = p1[1], qb2 = p1[2], qb3 = p1[3];
    float4 qb4 = p1[4], qb5 = p1[5], qb6 = p1[6], qb7 = p1[7];
    float4 qc0 = p2[0], qc1 = p2[1], qc2 = p2[2], qc3 = p2[3];
    float4 qc4 = p2[4], qc5 = p2[5], qc6 = p2[6], qc7 = p2[7];
    float4 qd0 = p3[0], qd1 = p3[1], qd2 = p3[2], qd3 = p3[3];
    float4 qd4 = p3[4], qd5 = p3[5], qd6 = p3[6], qd7 = p3[7];
    float4 qe0 = p4[0], qe1 = p4[1], qe2 = p4[2], qe3 = p4[3];
    float4 qe4 = p4[4], qe5 = p4[5], qe6 = p4[6], qe7 = p4[7];
    float4 qf0 = p5[0], qf1 = p5[1], qf2 = p5[2], qf3 = p5[3];
    float4 qf4 = p5[4], qf5 = p5[5], qf6 = p5[6], qf7 = p5[7];
    CVT2(A0,  A1,  qa0) CVT2(A2,  A3,  qa1) CVT2(A4,  A5,  qa2) CVT2(A6,  A7,  qa3)
    CVT2(A8,  A9,  qa4) CVT2(A10, A11, qa5) CVT2(A12, A13, qa6) CVT2(A14, A15, qa7)
    CVT2(B0,  B1,  qb0) CVT2(B2,  B3,  qb1) CVT2(B4,  B5,  qb2) CVT2(B6,  B7,  qb3)
    CVT2(B8,  B9,  qb4) CVT2(B10, B11, qb5) CVT2(B12, B13, qb6) CVT2(B14, B15, qb7)
    CVT2(C0,  C1,  qc0) CVT2(C2,  C3,  qc1) CVT2(C4,  C5,  qc2) CVT2(C6,  C7,  qc3)
    CVT2(C8,  C9,  qc4) CVT2(C10, C11, qc5) CVT2(C12, C13, qc6) CVT2(C14, C15, qc7)
    CVT2(D0,  D1,  qd0) CVT2(D2,  D3,  qd1) CVT2(D4,  D5,  qd2) CVT2(D6,  D7,  qd3)
    CVT2(D8,  D9,  qd4) CVT2(D10, D11, qd5) CVT2(D12, D13, qd6) CVT2(D14, D15, qd7)
    CVT2(E0,  E1,  qe0) CVT2(E2,  E3,  qe1) CVT2(E4,  E5,  qe2) CVT2(E6,  E7,  qe3)
    CVT2(E8,  E9,  qe4) CVT2(E10, E11, qe5) CVT2(E12, E13, qe6) CVT2(E14, E15, qe7)
    CVT2(F0,  F1,  qf0) CVT2(F2,  F3,  qf1) CVT2(F4,  F5,  qf2) CVT2(F6,  F7,  qf3)
    CVT2(F8,  F9,  qf4) CVT2(F10, F11, qf5) CVT2(F12, F13, qf6) CVT2(F14, F15, qf7)

    float wxa  = W_ih0[rowa];
    float wxb  = W_ih0[rowb];
    float bb0a = b_ih0[rowa] + b_hh0[rowa];
    float bb0b = b_ih0[rowb] + b_hh0[rowb];
    float bb1a = b_ih1[rowa] + b_hh1[rowa];
    float bb1b = b_ih1[rowb] + b_hh1[rowb];

    // Remat fences (R7/R9-proven). <=24 operands each (inline-asm limit margin).
    asm volatile("" : "+v"(A0), "+v"(A1), "+v"(A2),  "+v"(A3),
                      "+v"(A4), "+v"(A5), "+v"(A6),  "+v"(A7),
                      "+v"(A8), "+v"(A9), "+v"(A10), "+v"(A11),
                      "+v"(A12),"+v"(A13),"+v"(A14), "+v"(A15),
                      "+v"(B0), "+v"(B1), "+v"(B2),  "+v"(B3),
                      "+v"(B4), "+v"(B5), "+v"(B6),  "+v"(B7));
    asm volatile("" : "+v"(B8), "+v"(B9), "+v"(B10), "+v"(B11),
                      "+v"(B12),"+v"(B13),"+v"(B14), "+v"(B15),
                      "+v"(C0), "+v"(C1), "+v"(C2),  "+v"(C3),
                      "+v"(C4), "+v"(C5), "+v"(C6),  "+v"(C7),
                      "+v"(C8), "+v"(C9), "+v"(C10), "+v"(C11),
                      "+v"(C12),"+v"(C13),"+v"(C14), "+v"(C15));
    asm volatile("" : "+v"(D0), "+v"(D1), "+v"(D2),  "+v"(D3),
                      "+v"(D4), "+v"(D5), "+v"(D6),  "+v"(D7),
                      "+v"(D8), "+v"(D9), "+v"(D10), "+v"(D11),
                      "+v"(D12),"+v"(D13),"+v"(D14), "+v"(D15),
                      "+v"(E0), "+v"(E1), "+v"(E2),  "+v"(E3),
                      "+v"(E4), "+v"(E5), "+v"(E6),  "+v"(E7));
    asm volatile("" : "+v"(E8), "+v"(E9), "+v"(E10), "+v"(E11),
                      "+v"(E12),"+v"(E13),"+v"(E14), "+v"(E15),
                      "+v"(F0), "+v"(F1), "+v"(F2),  "+v"(F3),
                      "+v"(F4), "+v"(F5), "+v"(F6),  "+v"(F7),
                      "+v"(F8), "+v"(F9), "+v"(F10), "+v"(F11),
                      "+v"(F12),"+v"(F13),"+v"(F14), "+v"(F15));
    asm volatile("" : "+v"(wxa), "+v"(wxb), "+v"(bb0a),
                      "+v"(bb0b),"+v"(bb1a),"+v"(bb1b));

    // act(z) = mm * rcp(1 + exp(kk*z)) + aa ; tanh only for gate g (gidx==2).
    const bool isg = (gidx == 2);
    const float kk = isg ? -2.f : -1.f;
    const float mm = isg ?  2.f :  1.f;
    const float aa = isg ? -1.f :  0.f;

    const bool wlane = (pp == 1) && (uu == 0);   // h writers (f lanes)
    const int  hoffa = ss * HH + na;             // s=0 -> h0[n], s=1 -> h1[n]
    const int  hoffb = ss * HH + nb;
    float ccaP = 0.f, ccbP = 0.f;                // element P cell state
    float ccaQ = 0.f, ccbQ = 0.f;                // element Q cell state

    __syncthreads();

    // One fdot2 per chain per row; P and Q rows alternate -> 12 independent
    // chains, dependents spaced 12 instrs (24 issue-cyc).
    #define ROWP(Aj, Dj, Bj, Ej, Cj, Fj, Hv, Gv, e) \
        s0aP = FDOT2(Aj, H2V(Hv, e), s0aP); \
        s0bP = FDOT2(Dj, H2V(Hv, e), s0bP); \
        s1aP = FDOT2(Bj, H2V(Hv, e), s1aP); \
        s1bP = FDOT2(Ej, H2V(Hv, e), s1bP); \
        s2aP = FDOT2(Cj, H2V(Gv, e), s2aP); \
        s2bP = FDOT2(Fj, H2V(Gv, e), s2bP);
    #define ROWQ(Aj, Dj, Bj, Ej, Cj, Fj, Hv, Gv, e) \
        s0aQ = FDOT2(Aj, H2V(Hv, e), s0aQ); \
        s0bQ = FDOT2(Dj, H2V(Hv, e), s0bQ); \
        s1aQ = FDOT2(Bj, H2V(Hv, e), s1aQ); \
        s1bQ = FDOT2(Ej, H2V(Hv, e), s1bQ); \
        s2aQ = FDOT2(Cj, H2V(Gv, e), s2aQ); \
        s2bQ = FDOT2(Fj, H2V(Gv, e), s2bQ);

    for (int t = 0; t <= TT; ++t) {
        const int tc = (t < TT) ? t : 0;
        const float xtP = x_s[0][tc];
        const float xtQ = x_s[1][tc];
        const h8* hbP = (const h8*)hbuf[0][t & 1];
        const h8* hbQ = (const h8*)hbuf[1][t & 1];
        // Broadcast b128 reads for both elements, consumption-ordered.
        h8 HaP = hbP[4 * ss + 0], GaP = hbP[8 + 4 * ss + 0];
        h8 HaQ = hbQ[4 * ss + 0], GaQ = hbQ[8 + 4 * ss + 0];
        h8 HcP = hbP[4 * ss + 1], GcP = hbP[8 + 4 * ss + 1];
        h8 HcQ = hbQ[4 * ss + 1], GcQ = hbQ[8 + 4 * ss + 1];
        h8 HeP = hbP[4 * ss + 2], GeP = hbP[8 + 4 * ss + 2];
        h8 HeQ = hbQ[4 * ss + 2], GeQ = hbQ[8 + 4 * ss + 2];
        h8 HgP = hbP[4 * ss + 3], GgP = hbP[8 + 4 * ss + 3];
        h8 HgQ = hbQ[4 * ss + 3], GgQ = hbQ[8 + 4 * ss + 3];

        // 12 chains, 16 links each.
        float s0aP = ss ? 0.f : fmaf(xtP, wxa, bb0a);
        float s0bP = ss ? 0.f : fmaf(xtP, wxb, bb0b);
        float s1aP = ss ? 0.f : bb1a;
        float s1bP = ss ? 0.f : bb1b;
        float s2aP = 0.f, s2bP = 0.f;
        float s0aQ = ss ? 0.f : fmaf(xtQ, wxa, bb0a);
        float s0bQ = ss ? 0.f : fmaf(xtQ, wxb, bb0b);
        float s1aQ = ss ? 0.f : bb1a;
        float s1bQ = ss ? 0.f : bb1b;
        float s2aQ = 0.f, s2bQ = 0.f;

        ROWP(A0,  D0,  B0,  E0,  C0,  F0,  HaP, GaP, 0)
        ROWQ(A0,  D0,  B0,  E0,  C0,  F0,  HaQ, GaQ, 0)
        ROWP(A1,  D1,  B1,  E1,  C1,  F1,  HaP, GaP, 1)
        ROWQ(A1,  D1,  B1,  E1,  C1,  F1,  HaQ, GaQ, 1)
        ROWP(A2,  D2,  B2,  E2,  C2,  F2,  HaP, GaP, 2)
        ROWQ(A2,  D2,  B2,  E2,  C2,  F2,  HaQ, GaQ, 2)
        ROWP(A3,  D3,  B3,  E3,  C3,  F3,  HaP, GaP, 3)
        ROWQ(A3,  D3,  B3,  E3,  C3,  F3,  HaQ, GaQ, 3)
        ROWP(A4,  D4,  B4,  E4,  C4,  F4,  HcP, GcP, 0)
        ROWQ(A4,  D4,  B4,  E4,  C4,  F4,  HcQ, GcQ, 0)
        ROWP(A5,  D5,  B5,  E5,  C5,  F5,  HcP, GcP, 1)
        ROWQ(A5,  D5,  B5,  E5,  C5,  F5,  HcQ, GcQ, 1)
        ROWP(A6,  D6,  B6,  E6,  C6,  F6,  HcP, GcP, 2)
        ROWQ(A6,  D6,  B6,  E6,  C6,  F6,  HcQ, GcQ, 2)
        ROWP(A7,  D7,  B7,  E7,  C7,  F7,  HcP, GcP, 3)
        ROWQ(A7,  D7,  B7,  E7,  C7,  F7,  HcQ, GcQ, 3)
        ROWP(A8,  D8,  B8,  E8,  C8,  F8,  HeP, GeP, 0)
        ROWQ(A8,  D8,  B8,  E8,  C8,  F8,  HeQ, GeQ, 0)
        ROWP(A9,  D9,  B9,  E9,  C9,  F9,  HeP, GeP, 1)
        ROWQ(A9,  D9,  B9,  E9,  C9,  F9,  HeQ, GeQ, 1)
        ROWP(A10, D10, B10, E10, C10, F10, HeP, GeP, 2)
        ROWQ(A10, D10, B10, E10, C10, F10, HeQ, GeQ, 2)
        ROWP(A11, D11, B11, E11, C11, F11, HeP, GeP, 3)
        ROWQ(A11, D11, B11, E11, C11, F11, HeQ, GeQ, 3)
        ROWP(A12, D12, B12, E12, C12, F12, HgP, GgP, 0)
        ROWQ(A12, D12, B12, E12, C12, F12, HgQ, GgQ, 0)
        ROWP(A13, D13, B13, E13, C13, F13, HgP, GgP, 1)
        ROWQ(A13, D13, B13, E13, C13, F13, HgQ, GgQ, 1)
        ROWP(A14, D14, B14, E14, C14, F14, HgP, GgP, 2)
        ROWQ(A14, D14, B14, E14, C14, F14, HgQ, GgQ, 2)
        ROWP(A15, D15, B15, E15, C15, F15, HgP, GgP, 3)
        ROWQ(A15, D15, B15, E15, C15, F15, HgQ, GgQ, 3)

        float acc0aP = s0aP,        acc0bP = s0bP;
        float acc1aP = s1aP + s2aP, acc1bP = s1bP + s2bP;
        float acc0aQ = s0aQ,        acc0bQ = s0bQ;
        float acc1aQ = s1aQ + s2aQ, acc1bQ = s1bQ + s2bQ;

        // s-butterfly (DPP xor1): both s-lanes hold full row sums.
        acc0aP += dpp_mov<DPP_XOR1>(acc0aP);
        acc0bP += dpp_mov<DPP_XOR1>(acc0bP);
        acc1aP += dpp_mov<DPP_XOR1>(acc1aP);
        acc1bP += dpp_mov<DPP_XOR1>(acc1bP);
        acc0aQ += dpp_mov<DPP_XOR1>(acc0aQ);
        acc0bQ += dpp_mov<DPP_XOR1>(acc0bQ);
        acc1aQ += dpp_mov<DPP_XOR1>(acc1aQ);
        acc1bQ += dpp_mov<DPP_XOR1>(acc1bQ);

        // Per-lane layer: s=0 -> L0(t), s=1 -> L1(t-1). Two elements,
        // independent tails -> compiler interleaves their latencies.
        float zaP  = ss ? acc1aP : acc0aP;
        float zbP  = ss ? acc1bP : acc0bP;
        float zaQ  = ss ? acc1aQ : acc0aQ;
        float zbQ  = ss ? acc1bQ : acc0bQ;
        float ezaP = __expf(kk * zaP);
        float ezbP = __expf(kk * zbP);
        float ezaQ = __expf(kk * zaQ);
        float ezbQ = __expf(kk * zbQ);
        float vaP  = fmaf(mm, __builtin_amdgcn_rcpf(1.f + ezaP), aa);
        float vbP  = fmaf(mm, __builtin_amdgcn_rcpf(1.f + ezbP), aa);
        float vaQ  = fmaf(mm, __builtin_amdgcn_rcpf(1.f + ezaQ), aa);
        float vbQ  = fmaf(mm, __builtin_amdgcn_rcpf(1.f + ezbQ), aa);

        // Gate combine, all DPP (independent per n-path and element).
        float igqaP = vaP * dpp_mov<DPP_XOR2>(vaP);
        float igqbP = vbP * dpp_mov<DPP_XOR2>(vbP);
        float igqaQ = vaQ * dpp_mov<DPP_XOR2>(vaQ);
        float igqbQ = vbQ * dpp_mov<DPP_XOR2>(vbQ);
        float igaP  = dpp_mov<DPP_SHR4>(igqaP);
        float igbP  = dpp_mov<DPP_SHR4>(igqbP);
        float igaQ  = dpp_mov<DPP_SHR4>(igqaQ);
        float igbQ  = dpp_mov<DPP_SHR4>(igqbQ);
        float fbaP  = dpp_mov<DPP_FB>(vaP);
        float fbbP  = dpp_mov<DPP_FB>(vbP);
        float fbaQ  = dpp_mov<DPP_FB>(vaQ);
        float fbbQ  = dpp_mov<DPP_FB>(vbQ);
        float obaP  = dpp_mov<DPP_OB>(vaP);
        float obbP  = dpp_mov<DPP_OB>(vbP);
        float obaQ  = dpp_mov<DPP_OB>(vaQ);
        float obbQ  = dpp_mov<DPP_OB>(vbQ);

        float cnaP = fmaf(fbaP, ccaP, igaP);
        float cnbP = fmaf(fbbP, ccbP, igbP);
        float cnaQ = fmaf(fbaQ, ccaQ, igaQ);
        float cnbQ = fmaf(fbbQ, ccbQ, igbQ);
        float hnaP = obaP * ftanh(cnaP);
        float hnbP = obbP * ftanh(cnbP);
        float hnaQ = obaQ * ftanh(cnaQ);
        float hnbQ = obbQ * ftanh(cnbQ);
        bool ok = ss ? (t > 0) : (t < TT);       // L1 skip at 0, L0 at TT
        ccaP = ok ? cnaP : ccaP;
        ccbP = ok ? cnbP : ccbP;
        ccaQ = ok ? cnaQ : ccaQ;
        ccbQ = ok ? cnbQ : ccbQ;
        if (wlane && ok) {
            _Float16* hwP = hbuf[0][(t + 1) & 1];
            _Float16* hwQ = hbuf[1][(t + 1) & 1];
            hwP[hoffa] = (_Float16)hnaP;
            hwP[hoffb] = (_Float16)hnbP;
            hwQ[hoffa] = (_Float16)hnaQ;
            hwQ[hoffb] = (_Float16)hnbQ;
        }

        __syncthreads();                         // h exchange (double-buffered)
    }
    #undef ROWP
    #undef ROWQ

    // FC on final h1 = h1(TT-1), per element, in hbuf[e][(TT+1)&1][64..128).
    {
        const int e = tid >> 7;          // 0: element P, 1: element Q
        const int j = tid & (EE - 1);    // 0..127
        const _Float16* h1f = &hbuf[e][(TT + 1) & 1][HH];
        float acc = b_fc[j];
        const float4* wf = (const float4*)(W_fc + j * HH);
        #pragma unroll
        for (int k = 0; k < HH / 4; ++k) {
            float4 v = wf[k];
            acc = fmaf(v.x, (float)h1f[4*k+0], acc);
            acc = fmaf(v.y, (float)h1f[4*k+1], acc);
            acc = fmaf(v.z, (float)h1f[4*k+2], acc);
            acc = fmaf(v.w, (float)h1f[4*k+3], acc);
        }
        out[(size_t)(2 * b + e) * EE + j] = acc;
    }
}

extern "C" void kernel_launch(void* const* d_in, const int* in_sizes, int n_in,
                              void* d_out, int out_size, void* d_ws, size_t ws_size,
                              hipStream_t stream) {
    const float* x     = (const float*)d_in[0];
    const float* W_ih0 = (const float*)d_in[1];
    const float* W_hh0 = (const float*)d_in[2];
    const float* b_ih0 = (const float*)d_in[3];
    const float* b_hh0 = (const float*)d_in[4];
    const float* W_ih1 = (const float*)d_in[5];
    const float* W_hh1 = (const float*)d_in[6];
    const float* b_ih1 = (const float*)d_in[7];
    const float* b_hh1 = (const float*)d_in[8];
    const float* W_fc  = (const float*)d_in[9];
    const float* b_fc  = (const float*)d_in[10];
    float* out = (float*)d_out;

    lstm2_fc_kernel<<<dim3(NB / 2), dim3(256), 0, stream>>>(
        x, W_ih0, W_hh0, b_ih0, b_hh0, W_ih1, W_hh1, b_ih1, b_hh1, W_fc, b_fc, out);
}

// Round 7
// 2081.602 us; speedup vs baseline: 1.5215x; 1.5215x over previous
//
#include <hip/hip_runtime.h>

#define TT 4000   // timesteps
#define HH 64     // hidden
#define NB 256    // batch
#define EE 128    // fc out

typedef __attribute__((ext_vector_type(8))) _Float16 h8;
typedef __attribute__((ext_vector_type(4))) float f4;

__device__ __forceinline__ float ftanh(float x) {
    return fmaf(2.f, __builtin_amdgcn_rcpf(1.f + __expf(-2.f * x)), -1.f);
}
__device__ __forceinline__ float fsig(float x) {
    return __builtin_amdgcn_rcpf(1.f + __expf(-x));
}

#define MF(A, B, C) __builtin_amdgcn_mfma_f32_16x16x32_f16((A), (B), (C), 0, 0, 0)

// 8 consecutive fp32 -> h8 (one MFMA operand fragment, 4 VGPRs).
__device__ __forceinline__ h8 ld8h(const float* p) {
    f4 a = ((const f4*)p)[0], c = ((const f4*)p)[1];
    return h8{(_Float16)a.x, (_Float16)a.y, (_Float16)a.z, (_Float16)a.w,
              (_Float16)c.x, (_Float16)c.y, (_Float16)c.z, (_Float16)c.w};
}

// R20: matrix-pipe recurrence. R19's failure finalized the objective: all
// blocks are concurrent, so total = 4001 x ONE block's step time — only the
// per-step critical path matters. R17's 1131-cyc step is dominated by 96
// fdot2/lane VALU issue (~300-480cyc) + act tail + LDS/barrier. MfmaUtil
// was 0.0 all session: the matrix pipe is idle. Fix: per step per layer the
// matmul is h(64) x W(64x256), M=1. mfma_f32_16x16x32_f16 with ALL 16 A
// rows = h (each 16-lane k-group reads ONE LDS address -> rows replicate,
// garbage-free). Per wave: 4 gate-tiles x (2-chain L0 + 4-chain L1 [k=128:
// W_ih1|W_hh1 stacked]) = 24 MFMA ~= 120cyc matrix-pipe vs ~400 VALU.
// C layout (HW-verified m89): col=lane&15, row=(lane>>4)*4+reg -> real
// gates in lanes 0..15, .x of each acc. All 4 gates of hidden-unit n land
// in ONE lane -> cell update is lane-local; ALL DPP gate algebra deleted.
// k-slot consistency: A and B loaded with the same (kgrp,j)->k map, so the
// hardware's internal k order cancels. Weights as B fragments: lane holds
// W[g*64 + w*16 + (lane&15)][kgrp*8+j] — 24 h8 = 96 VGPRs (same budget).
// h-reads: 4 ds_read_b128/lane (was 8).
//
// Layer pipelining (verified R3-R10): iter t computes L0 gates(t) from
// h0(t-1) and L1 gates(t-1) from {h1(t-2), h0(t-1)}; hbuf[t&1] holds
// {h0(t-1), h1(t-2)}; writers store {h0(t), h1(t-1)} to hbuf[(t+1)&1].
// 1 barrier/step, h fp16 double-buffered.
__global__ __launch_bounds__(256, 1)
void lstm2_fc_kernel(const float* __restrict__ x,      // [B, T, 1]
                     const float* __restrict__ W_ih0,  // [256, 1]
                     const float* __restrict__ W_hh0,  // [256, 64]
                     const float* __restrict__ b_ih0,  // [256]
                     const float* __restrict__ b_hh0,  // [256]
                     const float* __restrict__ W_ih1,  // [256, 64]
                     const float* __restrict__ W_hh1,  // [256, 64]
                     const float* __restrict__ b_ih1,  // [256]
                     const float* __restrict__ b_hh1,  // [256]
                     const float* __restrict__ W_fc,   // [128, 64]
                     const float* __restrict__ b_fc,   // [128]
                     float* __restrict__ out)          // [B, 128]
{
    const int b    = blockIdx.x;
    const int tid  = threadIdx.x;     // 0..255
    const int w    = tid >> 6;        // wave 0..3 -> n-range [w*16, w*16+16)
    const int lane = tid & 63;
    const int cidx = lane & 15;       // tile column = n offset
    const int kgrp = lane >> 4;       // k-block 0..3
    const int n    = w * 16 + cidx;   // hidden index this lane owns (if act)
    const bool act = (kgrp == 0);     // lanes holding real (row-0) gates

    __shared__ float x_s[TT];                          // 16 KB
    __shared__ __align__(16) _Float16 hbuf[2][2 * HH]; // [parity][h0|h1], fp16

    for (int t = tid; t < TT; t += 256) x_s[t] = x[(size_t)b * TT + t];
    if (tid < 4 * HH) ((_Float16*)hbuf)[tid] = (_Float16)0.f;

    // Gate rows (PyTorch order i,f,g,o): row = g*64 + n.
    const int rI = 0 * HH + n, rF = 1 * HH + n, rG = 2 * HH + n, rO = 3 * HH + n;
    const int kb0 = kgrp * 8, kb1 = 32 + kgrp * 8;   // k-slot bases

    // --- B fragments: lane holds W[row(col=cidx)][k(kgrp,j)] ---
    // L0 (W_hh0, k=0..63 -> 2 frags/gate)
    h8 BI0a = ld8h(W_hh0 + rI * HH + kb0), BI0b = ld8h(W_hh0 + rI * HH + kb1);
    h8 BF0a = ld8h(W_hh0 + rF * HH + kb0), BF0b = ld8h(W_hh0 + rF * HH + kb1);
    h8 BG0a = ld8h(W_hh0 + rG * HH + kb0), BG0b = ld8h(W_hh0 + rG * HH + kb1);
    h8 BO0a = ld8h(W_hh0 + rO * HH + kb0), BO0b = ld8h(W_hh0 + rO * HH + kb1);
    // L1 x-part (W_ih1, pairs with A=h0)
    h8 BI1a = ld8h(W_ih1 + rI * HH + kb0), BI1b = ld8h(W_ih1 + rI * HH + kb1);
    h8 BF1a = ld8h(W_ih1 + rF * HH + kb0), BF1b = ld8h(W_ih1 + rF * HH + kb1);
    h8 BG1a = ld8h(W_ih1 + rG * HH + kb0), BG1b = ld8h(W_ih1 + rG * HH + kb1);
    h8 BO1a = ld8h(W_ih1 + rO * HH + kb0), BO1b = ld8h(W_ih1 + rO * HH + kb1);
    // L1 h-part (W_hh1, pairs with A=h1)
    h8 BI1c = ld8h(W_hh1 + rI * HH + kb0), BI1d = ld8h(W_hh1 + rI * HH + kb1);
    h8 BF1c = ld8h(W_hh1 + rF * HH + kb0), BF1d = ld8h(W_hh1 + rF * HH + kb1);
    h8 BG1c = ld8h(W_hh1 + rG * HH + kb0), BG1d = ld8h(W_hh1 + rG * HH + kb1);
    h8 BO1c = ld8h(W_hh1 + rO * HH + kb0), BO1d = ld8h(W_hh1 + rO * HH + kb1);

    // Per-lane bias/x-weight scalars (valid for this lane's col; only act
    // lanes' values are consumed).
    float wxI = W_ih0[rI], wxF = W_ih0[rF], wxG = W_ih0[rG], wxO = W_ih0[rO];
    float bI0 = b_ih0[rI] + b_hh0[rI], bF0 = b_ih0[rF] + b_hh0[rF];
    float bG0 = b_ih0[rG] + b_hh0[rG], bO0 = b_ih0[rO] + b_hh0[rO];
    float bI1 = b_ih1[rI] + b_hh1[rI], bF1 = b_ih1[rF] + b_hh1[rF];
    float bG1 = b_ih1[rG] + b_hh1[rG], bO1 = b_ih1[rO] + b_hh1[rO];

    // Remat fences (R7/R9-proven): keep fragments resident across the loop.
    asm volatile("" : "+v"(BI0a), "+v"(BI0b), "+v"(BF0a), "+v"(BF0b),
                      "+v"(BG0a), "+v"(BG0b), "+v"(BO0a), "+v"(BO0b),
                      "+v"(BI1a), "+v"(BI1b), "+v"(BF1a), "+v"(BF1b));
    asm volatile("" : "+v"(BG1a), "+v"(BG1b), "+v"(BO1a), "+v"(BO1b),
                      "+v"(BI1c), "+v"(BI1d), "+v"(BF1c), "+v"(BF1d),
                      "+v"(BG1c), "+v"(BG1d), "+v"(BO1c), "+v"(BO1d));
    asm volatile("" : "+v"(wxI), "+v"(wxF), "+v"(wxG), "+v"(wxO),
                      "+v"(bI0), "+v"(bF0), "+v"(bG0), "+v"(bO0),
                      "+v"(bI1), "+v"(bF1), "+v"(bG1), "+v"(bO1));

    float cc0 = 0.f, cc1 = 0.f;   // cell states (act lanes)

    __syncthreads();

    for (int t = 0; t <= TT; ++t) {
        const float xt = x_s[(t < TT) ? t : 0];
        const h8* hb = (const h8*)hbuf[t & 1];
        // A fragments: one address per k-group -> all 16 A-rows = h (replicated).
        h8 A0a = hb[kgrp],     A0b = hb[4 + kgrp];    // h0(t-1) k 0..31 | 32..63
        h8 A1a = hb[8 + kgrp], A1b = hb[12 + kgrp];   // h1(t-2) k 0..31 | 32..63

        // C init: row-0 lanes get bias (+ x*W_ih0 for L0); garbage rows 0.
        f4 aI0 = {act ? fmaf(xt, wxI, bI0) : 0.f, 0.f, 0.f, 0.f};
        f4 aF0 = {act ? fmaf(xt, wxF, bF0) : 0.f, 0.f, 0.f, 0.f};
        f4 aG0 = {act ? fmaf(xt, wxG, bG0) : 0.f, 0.f, 0.f, 0.f};
        f4 aO0 = {act ? fmaf(xt, wxO, bO0) : 0.f, 0.f, 0.f, 0.f};
        f4 aI1 = {act ? bI1 : 0.f, 0.f, 0.f, 0.f};
        f4 aF1 = {act ? bF1 : 0.f, 0.f, 0.f, 0.f};
        f4 aG1 = {act ? bG1 : 0.f, 0.f, 0.f, 0.f};
        f4 aO1 = {act ? bO1 : 0.f, 0.f, 0.f, 0.f};

        // L0: gates(t) = h0(t-1) @ W_hh0^T + (bias + x*W_ih0)   [2-chain x4]
        aI0 = MF(A0a, BI0a, aI0); aF0 = MF(A0a, BF0a, aF0);
        aG0 = MF(A0a, BG0a, aG0); aO0 = MF(A0a, BO0a, aO0);
        aI0 = MF(A0b, BI0b, aI0); aF0 = MF(A0b, BF0b, aF0);
        aG0 = MF(A0b, BG0b, aG0); aO0 = MF(A0b, BO0b, aO0);
        // L1: gates(t-1) = h0(t-1) @ W_ih1^T + h1(t-2) @ W_hh1^T + bias [4-chain x4]
        aI1 = MF(A0a, BI1a, aI1); aF1 = MF(A0a, BF1a, aF1);
        aG1 = MF(A0a, BG1a, aG1); aO1 = MF(A0a, BO1a, aO1);
        aI1 = MF(A0b, BI1b, aI1); aF1 = MF(A0b, BF1b, aF1);
        aG1 = MF(A0b, BG1b, aG1); aO1 = MF(A0b, BO1b, aO1);
        aI1 = MF(A1a, BI1c, aI1); aF1 = MF(A1a, BF1c, aF1);
        aG1 = MF(A1a, BG1c, aG1); aO1 = MF(A1a, BO1c, aO1);
        aI1 = MF(A1b, BI1d, aI1); aF1 = MF(A1b, BF1d, aF1);
        aG1 = MF(A1b, BG1d, aG1); aO1 = MF(A1b, BO1d, aO1);

        // Lane-local cell update (gates of n all in this lane's .x).
        float i0 = fsig(aI0.x), f0v = fsig(aF0.x);
        float g0 = ftanh(aG0.x), o0 = fsig(aO0.x);
        float i1 = fsig(aI1.x), f1v = fsig(aF1.x);
        float g1 = ftanh(aG1.x), o1 = fsig(aO1.x);
        float nc0 = fmaf(f0v, cc0, i0 * g0);
        float nc1 = fmaf(f1v, cc1, i1 * g1);
        const bool ok0 = (t < TT), ok1 = (t > 0);
        cc0 = ok0 ? nc0 : cc0;
        cc1 = ok1 ? nc1 : cc1;
        float h0n = o0 * ftanh(nc0);
        float h1n = o1 * ftanh(nc1);
        _Float16* hw = hbuf[(t + 1) & 1];
        if (act && ok0) hw[n] = (_Float16)h0n;
        if (act && ok1) hw[HH + n] = (_Float16)h1n;

        __syncthreads();                         // h exchange (double-buffered)
    }

    // FC on final h1 = h1(TT-1), in hbuf[(TT+1)&1][64..128).
    if (tid < EE) {
        const _Float16* h1f = &hbuf[(TT + 1) & 1][HH];
        float acc = b_fc[tid];
        const float4* wf = (const float4*)(W_fc + tid * HH);
        #pragma unroll
        for (int k = 0; k < HH / 4; ++k) {
            float4 v = wf[k];
            acc = fmaf(v.x, (float)h1f[4*k+0], acc);
            acc = fmaf(v.y, (float)h1f[4*k+1], acc);
            acc = fmaf(v.z, (float)h1f[4*k+2], acc);
            acc = fmaf(v.w, (float)h1f[4*k+3], acc);
        }
        out[(size_t)b * EE + tid] = acc;
    }
}

extern "C" void kernel_launch(void* const* d_in, const int* in_sizes, int n_in,
                              void* d_out, int out_size, void* d_ws, size_t ws_size,
                              hipStream_t stream) {
    const float* x     = (const float*)d_in[0];
    const float* W_ih0 = (const float*)d_in[1];
    const float* W_hh0 = (const float*)d_in[2];
    const float* b_ih0 = (const float*)d_in[3];
    const float* b_hh0 = (const float*)d_in[4];
    const float* W_ih1 = (const float*)d_in[5];
    const float* W_hh1 = (const float*)d_in[6];
    const float* b_ih1 = (const float*)d_in[7];
    const float* b_hh1 = (const float*)d_in[8];
    const float* W_fc  = (const float*)d_in[9];
    const float* b_fc  = (const float*)d_in[10];
    float* out = (float*)d_out;

    lstm2_fc_kernel<<<dim3(NB), dim3(256), 0, stream>>>(
        x, W_ih0, W_hh0, b_ih0, b_hh0, W_ih1, W_hh1, b_ih1, b_hh1, W_fc, b_fc, out);
}